// Round 1
// baseline (405.634 us; speedup 1.0000x reference)
//
#include <hip/hip_runtime.h>
#include <hip/hip_bf16.h>

#define D 768
#define H 8
#define HD 96
#define MLP 3072
#define NB 2048
#define BATCH 4

typedef __attribute__((ext_vector_type(8))) short short8;
typedef __attribute__((ext_vector_type(4))) short short4v;
typedef __attribute__((ext_vector_type(4))) float f32x4;

__device__ inline short f2b(float f){
  unsigned u = __float_as_uint(f);
  unsigned r = (u + 0x7FFFu + ((u>>16)&1u)) >> 16;
  return (short)(unsigned short)r;
}
__device__ inline float b2f(short s){
  return __uint_as_float(((unsigned)(unsigned short)s) << 16);
}

// ---- weight transpose+convert: f32 in[K][Nc] -> bf16 out[Nc][K] (B^T layout)
__global__ __launch_bounds__(256) void wtrans(const float* __restrict__ in, short* __restrict__ out, int K, int Nc){
  __shared__ float tile[32][33];
  int bk = blockIdx.x, bn = blockIdx.y;
  int tx = threadIdx.x & 31, ty = threadIdx.x >> 5;
  #pragma unroll
  for (int i=0;i<4;++i)
    tile[ty + i*8][tx] = in[(size_t)(bk*32 + ty + i*8)*Nc + bn*32 + tx];
  __syncthreads();
  #pragma unroll
  for (int i=0;i<4;++i)
    out[(size_t)(bn*32 + ty + i*8)*K + bk*32 + tx] = f2b(tile[tx][ty + i*8]);
}

__global__ __launch_bounds__(256) void bias_cat(const float* __restrict__ bq, const float* __restrict__ bk,
                                                const float* __restrict__ bv, float* __restrict__ o){
  int i = blockIdx.x*256 + threadIdx.x;
  if (i < 768){ o[i]=bq[i]; o[768+i]=bk[i]; o[1536+i]=bv[i]; }
}

__global__ __launch_bounds__(256) void cvt_pb(const float* __restrict__ in, short* __restrict__ out){
  int i = blockIdx.x*256 + threadIdx.x;
  f32x4 v = *(const f32x4*)&in[(size_t)i*4];
  short4v o;
  o[0]=f2b(v[0]); o[1]=f2b(v[1]); o[2]=f2b(v[2]); o[3]=f2b(v[3]);
  *(short4v*)&out[(size_t)i*4] = o;
}

// ---- LayerNorm: f32 [rows][768] -> bf16
__global__ __launch_bounds__(256) void ln_k(const float* __restrict__ X, const float* __restrict__ gg,
                                            const float* __restrict__ bb, short* __restrict__ out){
  int row = blockIdx.x, t = threadIdx.x;
  const float* x = X + (size_t)row*D;
  float v0=x[t], v1=x[t+256], v2=x[t+512];
  float s=v0+v1+v2, ss=v0*v0+v1*v1+v2*v2;
  #pragma unroll
  for (int m=1;m<64;m<<=1){ s += __shfl_xor(s,m); ss += __shfl_xor(ss,m); }
  __shared__ float red[8];
  int w=t>>6, lane=t&63;
  if (!lane){ red[w]=s; red[4+w]=ss; }
  __syncthreads();
  s = red[0]+red[1]+red[2]+red[3];
  ss = red[4]+red[5]+red[6]+red[7];
  float mu = s*(1.f/768.f);
  float inv = rsqrtf(ss*(1.f/768.f) - mu*mu + 1e-5f);
  short* o = out + (size_t)row*D;
  o[t]     = f2b((v0-mu)*inv*gg[t]     + bb[t]);
  o[t+256] = f2b((v1-mu)*inv*gg[t+256] + bb[t+256]);
  o[t+512] = f2b((v2-mu)*inv*gg[t+512] + bb[t+512]);
}

// ---- GEMM: C[M][Nc] = A[M][K] (bf16) @ Bt[Nc][K]^T (bf16) + bias, epilogue per MODE
// MODE 0: +bias -> bf16 out
// MODE 1: +bias +resid(f32) -> f32 out
// MODE 2: +bias, exact-erf GELU -> bf16 out
// MODE 3: +bias +resid(f32) -> f32 out
template<int MODE>
__global__ __launch_bounds__(256) void gemm_bt(
    const short* __restrict__ A, const short* __restrict__ Bt,
    const float* __restrict__ bias, const float* __restrict__ resid,
    void* __restrict__ Cout, int Nc, int K)
{
  __shared__ __align__(16) short As[128][40];
  __shared__ __align__(16) short Bs[128][40];
  int m0 = blockIdx.x*128, n0 = blockIdx.y*128;
  int t = threadIdx.x;
  int lane = t & 63, w = t >> 6;
  int wm = w >> 1, wn = w & 1;
  int r = lane & 15, g = lane >> 4;
  f32x4 acc[4][4] = {};
  int nst = K >> 5;
  for (int kt=0; kt<nst; ++kt){
    #pragma unroll
    for (int i=0;i<2;++i){
      int c = t + i*256;
      int row = c >> 2, off = (c & 3)*8;
      *(short8*)&As[row][off] = *(const short8*)&A[(size_t)(m0+row)*K + kt*32 + off];
      *(short8*)&Bs[row][off] = *(const short8*)&Bt[(size_t)(n0+row)*K + kt*32 + off];
    }
    __syncthreads();
    short8 af[4], bfr[4];
    #pragma unroll
    for (int i=0;i<4;++i){
      af[i]  = *(const short8*)&As[wm*64 + i*16 + r][g*8];
      bfr[i] = *(const short8*)&Bs[wn*64 + i*16 + r][g*8];
    }
    #pragma unroll
    for (int i=0;i<4;++i)
      #pragma unroll
      for (int j=0;j<4;++j)
        acc[i][j] = __builtin_amdgcn_mfma_f32_16x16x32_bf16(af[i], bfr[j], acc[i][j], 0,0,0);
    __syncthreads();
  }
  #pragma unroll
  for (int i=0;i<4;++i){
    #pragma unroll
    for (int j=0;j<4;++j){
      int col = n0 + wn*64 + j*16 + r;
      float bv = bias[col];
      #pragma unroll
      for (int q=0;q<4;++q){
        int row = m0 + wm*64 + i*16 + g*4 + q;
        size_t idx = (size_t)row*Nc + col;
        float val = acc[i][j][q] + bv;
        if constexpr (MODE==0){
          ((short*)Cout)[idx] = f2b(val);
        } else if constexpr (MODE==1){
          ((float*)Cout)[idx] = val + resid[idx];
        } else if constexpr (MODE==2){
          float ge = 0.5f*val*(1.f + erff(val*0.70710678118654752f));
          ((short*)Cout)[idx] = f2b(ge);
        } else {
          ((float*)Cout)[idx] = val + resid[idx];
        }
      }
    }
  }
}

// ---- V transpose: qkv v-slice -> v_t[(b*H+h)*HD + d][NB]
__global__ __launch_bounds__(256) void vtrans(const short* __restrict__ qkv, short* __restrict__ v_t){
  int bx = blockIdx.x;
  int nt = bx & 31, h = (bx>>5)&7, b = bx>>8;
  __shared__ short tile[64][97];
  int t = threadIdx.x;
  #pragma unroll
  for (int i=0;i<3;++i){
    int c = t + i*256;
    int rr = c/12, off = (c%12)*8;
    short8 vv = *(const short8*)&qkv[(size_t)(b*NB + nt*64 + rr)*2304 + 1536 + h*HD + off];
    #pragma unroll
    for (int j=0;j<8;++j) tile[rr][off+j] = vv[j];
  }
  __syncthreads();
  #pragma unroll
  for (int i=0;i<24;++i){
    int idx = t + i*256;
    int d = idx >> 6, n = idx & 63;
    v_t[((size_t)((b*H + h)*HD + d))*NB + nt*64 + n] = tile[n][d];
  }
}

// ---- Flash attention: per (b,h,128-row q tile); KVBLK=64; online softmax
__global__ __launch_bounds__(256) void attn_k(const short* __restrict__ qkv, const short* __restrict__ v_t,
                                              const short* __restrict__ pb, short* __restrict__ aout){
  int bx = blockIdx.x;
  int qb = bx & 15, h = (bx>>4)&7, b = bx>>7;
  int t = threadIdx.x, lane = t&63, w = t>>6;
  int r = lane&15, g = lane>>4;
  __shared__ __align__(16) short Ks[64][104];
  __shared__ __align__(16) short Vs[96][72];
  __shared__ __align__(16) short Ps[4][32][72];
  const float SCALE = 0.10206207261596575f;   // 1/sqrt(96)
  short8 qa[2][3];
  #pragma unroll
  for (int m=0;m<2;++m)
    #pragma unroll
    for (int ks=0;ks<3;++ks)
      qa[m][ks] = *(const short8*)&qkv[(size_t)(b*NB + qb*128 + w*32 + m*16 + r)*2304 + h*HD + ks*32 + g*8];
  f32x4 oacc[2][6] = {};
  float m_run[2][4], l_run[2][4];
  #pragma unroll
  for (int m=0;m<2;++m)
    #pragma unroll
    for (int j=0;j<4;++j){ m_run[m][j] = -1e30f; l_run[m][j] = 0.f; }
  for (int kt=0; kt<32; ++kt){
    int kbase = kt*64;
    #pragma unroll
    for (int i=0;i<3;++i){
      int c = t + i*256;
      int rr = c/12, off = (c%12)*8;
      *(short8*)&Ks[rr][off] = *(const short8*)&qkv[(size_t)(b*NB + kbase + rr)*2304 + 768 + h*HD + off];
    }
    #pragma unroll
    for (int i=0;i<3;++i){
      int c = t + i*256;
      int rr = c>>3, off = (c&7)*8;
      *(short8*)&Vs[rr][off] = *(const short8*)&v_t[((size_t)((b*H+h)*HD + rr))*NB + kbase + off];
    }
    __syncthreads();
    f32x4 sacc[2][4] = {};
    #pragma unroll
    for (int ks=0;ks<3;++ks){
      short8 kb[4];
      #pragma unroll
      for (int n=0;n<4;++n) kb[n] = *(const short8*)&Ks[n*16 + r][ks*32 + g*8];
      #pragma unroll
      for (int m=0;m<2;++m)
        #pragma unroll
        for (int n=0;n<4;++n)
          sacc[m][n] = __builtin_amdgcn_mfma_f32_16x16x32_bf16(qa[m][ks], kb[n], sacc[m][n], 0,0,0);
    }
    // online softmax (C-frag layout: row=g*4+j, col=n*16+r)
    #pragma unroll
    for (int m=0;m<2;++m){
      #pragma unroll
      for (int j=0;j<4;++j){
        int qrl = qb*128 + w*32 + m*16 + g*4 + j;
        float vals[4];
        #pragma unroll
        for (int n=0;n<4;++n)
          vals[n] = sacc[m][n][j]*SCALE + b2f(pb[(size_t)qrl*NB + kbase + n*16 + r]);
        float pmax = fmaxf(fmaxf(vals[0],vals[1]), fmaxf(vals[2],vals[3]));
        pmax = fmaxf(pmax, __shfl_xor(pmax,1));
        pmax = fmaxf(pmax, __shfl_xor(pmax,2));
        pmax = fmaxf(pmax, __shfl_xor(pmax,4));
        pmax = fmaxf(pmax, __shfl_xor(pmax,8));
        float mnew = fmaxf(m_run[m][j], pmax);
        float f = __expf(m_run[m][j] - mnew);
        float rs = 0.f;
        #pragma unroll
        for (int n=0;n<4;++n){
          float pe = __expf(vals[n] - mnew);
          rs += pe;
          Ps[w][m*16 + g*4 + j][n*16 + r] = f2b(pe);
        }
        rs += __shfl_xor(rs,1); rs += __shfl_xor(rs,2);
        rs += __shfl_xor(rs,4); rs += __shfl_xor(rs,8);
        l_run[m][j] = l_run[m][j]*f + rs;
        m_run[m][j] = mnew;
        #pragma unroll
        for (int n=0;n<6;++n) oacc[m][n][j] *= f;
      }
    }
    // PV (Ps is per-wave private; no cross-wave barrier needed here)
    #pragma unroll
    for (int ks2=0;ks2<2;++ks2){
      short8 pa[2], vb[6];
      #pragma unroll
      for (int m=0;m<2;++m) pa[m] = *(const short8*)&Ps[w][m*16 + r][ks2*32 + g*8];
      #pragma unroll
      for (int n=0;n<6;++n) vb[n] = *(const short8*)&Vs[n*16 + r][ks2*32 + g*8];
      #pragma unroll
      for (int m=0;m<2;++m)
        #pragma unroll
        for (int n=0;n<6;++n)
          oacc[m][n] = __builtin_amdgcn_mfma_f32_16x16x32_bf16(pa[m], vb[n], oacc[m][n], 0,0,0);
    }
    __syncthreads();
  }
  #pragma unroll
  for (int m=0;m<2;++m){
    float inv[4];
    #pragma unroll
    for (int j=0;j<4;++j) inv[j] = 1.f / l_run[m][j];
    #pragma unroll
    for (int n=0;n<6;++n){
      #pragma unroll
      for (int j=0;j<4;++j){
        int rowg = b*NB + qb*128 + w*32 + m*16 + g*4 + j;
        int col = h*HD + n*16 + r;
        aout[(size_t)rowg*D + col] = f2b(oacc[m][n][j]*inv[j]);
      }
    }
  }
}

extern "C" void kernel_launch(void* const* d_in, const int* in_sizes, int n_in,
                              void* d_out, int out_size, void* d_ws, size_t ws_size,
                              hipStream_t stream){
  const float* x   = (const float*)d_in[0];
  const float* pb  = (const float*)d_in[1];
  const float* wq  = (const float*)d_in[2];
  const float* bq  = (const float*)d_in[3];
  const float* wk  = (const float*)d_in[4];
  const float* bk  = (const float*)d_in[5];
  const float* wv  = (const float*)d_in[6];
  const float* bv  = (const float*)d_in[7];
  const float* wo  = (const float*)d_in[8];
  const float* bo  = (const float*)d_in[9];
  const float* g1  = (const float*)d_in[10];
  const float* b1  = (const float*)d_in[11];
  const float* g2  = (const float*)d_in[12];
  const float* b2  = (const float*)d_in[13];
  const float* wf1 = (const float*)d_in[14];
  const float* bf1 = (const float*)d_in[15];
  const float* wf2 = (const float*)d_in[16];
  const float* bf2 = (const float*)d_in[17];
  float* out = (float*)d_out;

  char* p = (char*)d_ws;
  auto alloc = [&](size_t bytes){ char* q = p; p += (bytes + 255) & ~(size_t)255; return q; };
  short* wqkv_t = (short*)alloc((size_t)2304*768*2);
  short* wo_t   = (short*)alloc((size_t)768*768*2);
  short* w1_t   = (short*)alloc((size_t)3072*768*2);
  short* w2_t   = (short*)alloc((size_t)768*3072*2);
  float* bqkv   = (float*)alloc(2304*4);
  short* pb16   = (short*)alloc((size_t)2048*2048*2);
  short* n1     = (short*)alloc((size_t)8192*768*2);   // reused as attn_out
  float* x1     = (float*)alloc((size_t)8192*768*4);
  short* n2     = (short*)alloc((size_t)8192*768*2);
  short* qkv    = (short*)alloc((size_t)8192*2304*2);
  short* v_t    = (short*)alloc((size_t)32*96*2048*2);
  short* hbuf   = qkv;      // aliases qkv+v_t (both dead after attention)
  short* attn_o = n1;       // n1 dead after QKV GEMM

  wtrans<<<dim3(24,24),256,0,stream>>>(wq, wqkv_t,               768, 768);
  wtrans<<<dim3(24,24),256,0,stream>>>(wk, wqkv_t + 768*768,     768, 768);
  wtrans<<<dim3(24,24),256,0,stream>>>(wv, wqkv_t + 2*768*768,   768, 768);
  wtrans<<<dim3(24,24),256,0,stream>>>(wo, wo_t, 768, 768);
  wtrans<<<dim3(24,96),256,0,stream>>>(wf1, w1_t, 768, 3072);
  wtrans<<<dim3(96,24),256,0,stream>>>(wf2, w2_t, 3072, 768);
  bias_cat<<<3,256,0,stream>>>(bq,bk,bv,bqkv);
  cvt_pb<<<4096,256,0,stream>>>(pb, pb16);
  ln_k<<<8192,256,0,stream>>>(x, g1, b1, n1);
  gemm_bt<0><<<dim3(64,18),256,0,stream>>>(n1, wqkv_t, bqkv, nullptr, qkv, 2304, 768);
  vtrans<<<1024,256,0,stream>>>(qkv, v_t);
  attn_k<<<512,256,0,stream>>>(qkv, v_t, pb16, attn_o);
  gemm_bt<1><<<dim3(64,6),256,0,stream>>>(attn_o, wo_t, bo, x, x1, 768, 768);
  ln_k<<<8192,256,0,stream>>>(x1, g2, b2, n2);
  gemm_bt<2><<<dim3(64,24),256,0,stream>>>(n2, w1_t, bf1, nullptr, hbuf, 3072, 768);
  gemm_bt<3><<<dim3(64,6),256,0,stream>>>(hbuf, w2_t, bf2, x1, out, 768, 3072);
}

// Round 2
// 387.334 us; speedup vs baseline: 1.0472x; 1.0472x over previous
//
#include <hip/hip_runtime.h>
#include <hip/hip_bf16.h>

#define D 768
#define H 8
#define HD 96
#define MLP 3072
#define NB 2048
#define BATCH 4

typedef __attribute__((ext_vector_type(8))) short short8;
typedef __attribute__((ext_vector_type(4))) short short4v;
typedef __attribute__((ext_vector_type(4))) float f32x4;

typedef const __attribute__((address_space(1))) unsigned int gu32;
typedef __attribute__((address_space(3))) unsigned int lu32;

__device__ inline void gload16(const void* g, void* l){
  __builtin_amdgcn_global_load_lds((gu32*)g, (lu32*)l, 16, 0, 0);
}

__device__ inline short f2b(float f){
  __hip_bfloat16 h = __float2bfloat16(f);
  return *reinterpret_cast<short*>(&h);
}
__device__ inline float b2f(short s){
  return __uint_as_float(((unsigned)(unsigned short)s) << 16);
}
__device__ inline float fexp2(float x){ return __builtin_amdgcn_exp2f(x); }

// ---- weight transpose+convert: f32 in[K][Nc] -> bf16 out[Nc][K] (B^T layout)
__global__ __launch_bounds__(256) void wtrans(const float* __restrict__ in, short* __restrict__ out, int K, int Nc){
  __shared__ float tile[32][33];
  int bk = blockIdx.x, bn = blockIdx.y;
  int tx = threadIdx.x & 31, ty = threadIdx.x >> 5;
  #pragma unroll
  for (int i=0;i<4;++i)
    tile[ty + i*8][tx] = in[(size_t)(bk*32 + ty + i*8)*Nc + bn*32 + tx];
  __syncthreads();
  #pragma unroll
  for (int i=0;i<4;++i)
    out[(size_t)(bn*32 + ty + i*8)*K + bk*32 + tx] = f2b(tile[tx][ty + i*8]);
}

__global__ __launch_bounds__(256) void bias_cat(const float* __restrict__ bq, const float* __restrict__ bk,
                                                const float* __restrict__ bv, float* __restrict__ o){
  int i = blockIdx.x*256 + threadIdx.x;
  if (i < 768){ o[i]=bq[i]; o[768+i]=bk[i]; o[1536+i]=bv[i]; }
}

// position bias -> bf16, pre-multiplied by log2(e) (softmax runs in log2 domain)
__global__ __launch_bounds__(256) void cvt_pb(const float* __restrict__ in, short* __restrict__ out){
  int i = blockIdx.x*256 + threadIdx.x;
  const float L2E = 1.4426950408889634f;
  f32x4 v = *(const f32x4*)&in[(size_t)i*4];
  short4v o;
  o[0]=f2b(v[0]*L2E); o[1]=f2b(v[1]*L2E); o[2]=f2b(v[2]*L2E); o[3]=f2b(v[3]*L2E);
  *(short4v*)&out[(size_t)i*4] = o;
}

// ---- LayerNorm: f32 [rows][768] -> bf16
__global__ __launch_bounds__(256) void ln_k(const float* __restrict__ X, const float* __restrict__ gg,
                                            const float* __restrict__ bb, short* __restrict__ out){
  int row = blockIdx.x, t = threadIdx.x;
  const float* x = X + (size_t)row*D;
  float v0=x[t], v1=x[t+256], v2=x[t+512];
  float s=v0+v1+v2, ss=v0*v0+v1*v1+v2*v2;
  #pragma unroll
  for (int m=1;m<64;m<<=1){ s += __shfl_xor(s,m); ss += __shfl_xor(ss,m); }
  __shared__ float red[8];
  int w=t>>6, lane=t&63;
  if (!lane){ red[w]=s; red[4+w]=ss; }
  __syncthreads();
  s = red[0]+red[1]+red[2]+red[3];
  ss = red[4]+red[5]+red[6]+red[7];
  float mu = s*(1.f/768.f);
  float inv = rsqrtf(ss*(1.f/768.f) - mu*mu + 1e-5f);
  short* o = out + (size_t)row*D;
  o[t]     = f2b((v0-mu)*inv*gg[t]     + bb[t]);
  o[t+256] = f2b((v1-mu)*inv*gg[t+256] + bb[t+256]);
  o[t+512] = f2b((v2-mu)*inv*gg[t+512] + bb[t+512]);
}

// ---- GEMM (m97 structure): C[M][Nc] = A[M][K] @ Bt[Nc][K]^T + bias, epilogue per MODE
// MODE 0: +bias -> bf16   | MODE 1: +bias +resid -> f32
// MODE 2: +bias, erf-GELU -> bf16 | MODE 3: +bias +resid -> f32
template<int MODE>
__global__ __launch_bounds__(256) void gemm_bt(
    const short* __restrict__ A, const short* __restrict__ Bt,
    const float* __restrict__ bias, const float* __restrict__ resid,
    void* __restrict__ Cout, int Nc, int K)
{
  __shared__ __align__(16) short As[128][32];
  __shared__ __align__(16) short Bs[128][32];
  int m0 = blockIdx.x*128, n0 = blockIdx.y*128;
  int t = threadIdx.x;
  int lane = t & 63, w = t >> 6;
  int wm = w >> 1, wn = w & 1;
  int r = lane & 15, g = lane >> 4;
  // staging source: row t>>2 (0..63), chunk (t&3)*8 shorts; second round +64 rows
  const short* aSrc = A  + (size_t)(m0 + (t>>2))*K + (t&3)*8;
  const short* bSrc = Bt + (size_t)(n0 + (t>>2))*K + (t&3)*8;
  char* aDst0 = (char*)As + w*1024;
  char* aDst1 = (char*)As + 4096 + w*1024;
  char* bDst0 = (char*)Bs + w*1024;
  char* bDst1 = (char*)Bs + 4096 + w*1024;
  size_t rowK64 = (size_t)64*K;
  f32x4 acc[4][4] = {};
  for (int kt=0; kt<K; kt+=32){
    gload16(aSrc + kt,          aDst0);
    gload16(aSrc + kt + rowK64, aDst1);
    gload16(bSrc + kt,          bDst0);
    gload16(bSrc + kt + rowK64, bDst1);
    __syncthreads();
    short8 af[4], bfr[4];
    #pragma unroll
    for (int i=0;i<4;++i){
      af[i]  = *(const short8*)&As[wm*64 + i*16 + r][g*8];
      bfr[i] = *(const short8*)&Bs[wn*64 + i*16 + r][g*8];
    }
    #pragma unroll
    for (int i=0;i<4;++i)
      #pragma unroll
      for (int j=0;j<4;++j)
        acc[i][j] = __builtin_amdgcn_mfma_f32_16x16x32_bf16(af[i], bfr[j], acc[i][j], 0,0,0);
    __syncthreads();
  }
  #pragma unroll
  for (int i=0;i<4;++i){
    #pragma unroll
    for (int j=0;j<4;++j){
      int col = n0 + wn*64 + j*16 + r;
      float bv = bias[col];
      #pragma unroll
      for (int q=0;q<4;++q){
        int row = m0 + wm*64 + i*16 + g*4 + q;
        size_t idx = (size_t)row*Nc + col;
        float val = acc[i][j][q] + bv;
        if constexpr (MODE==0){
          ((short*)Cout)[idx] = f2b(val);
        } else if constexpr (MODE==1){
          ((float*)Cout)[idx] = val + resid[idx];
        } else if constexpr (MODE==2){
          float ge = 0.5f*val*(1.f + erff(val*0.70710678118654752f));
          ((short*)Cout)[idx] = f2b(ge);
        } else {
          ((float*)Cout)[idx] = val + resid[idx];
        }
      }
    }
  }
}

// ---- V transpose: qkv v-slice -> v_t[(b*H+h)*HD + d][NB]
__global__ __launch_bounds__(256) void vtrans(const short* __restrict__ qkv, short* __restrict__ v_t){
  int bx = blockIdx.x;
  int nt = bx & 31, h = (bx>>5)&7, b = bx>>8;
  __shared__ short tile[64][97];
  int t = threadIdx.x;
  #pragma unroll
  for (int i=0;i<3;++i){
    int c = t + i*256;
    int rr = c/12, off = (c%12)*8;
    short8 vv = *(const short8*)&qkv[(size_t)(b*NB + nt*64 + rr)*2304 + 1536 + h*HD + off];
    #pragma unroll
    for (int j=0;j<8;++j) tile[rr][off+j] = vv[j];
  }
  __syncthreads();
  #pragma unroll
  for (int i=0;i<24;++i){
    int idx = t + i*256;
    int d = idx >> 6, n = idx & 63;
    v_t[((size_t)((b*H + h)*HD + d))*NB + nt*64 + n] = tile[n][d];
  }
}

// ---- Flash attention: 512 threads = 8 waves x 16 q-rows; KVBLK=64; log2-domain online softmax
__global__ __launch_bounds__(512, 4) void attn_k(const short* __restrict__ qkv, const short* __restrict__ v_t,
                                                 const short* __restrict__ pb, short* __restrict__ aout){
  int bx = blockIdx.x;
  int qb = bx & 15, h = (bx>>4)&7, b = bx>>7;
  int t = threadIdx.x, lane = t&63, w = t>>6;
  int r = lane&15, g = lane>>4;
  __shared__ __align__(16) short Ks[64][96];   // linear (global_load_lds)
  __shared__ __align__(16) short Vs[96][64];   // chunk-XOR swizzled via source
  __shared__ __align__(16) short Ps[8][16][72];
  const float SCALE2 = 0.10206207261596575f * 1.4426950408889634f;  // 1/sqrt(96) * log2(e)
  // Q fragment: rows w*16 + r
  short8 qa[3];
  #pragma unroll
  for (int ks=0;ks<3;++ks)
    qa[ks] = *(const short8*)&qkv[(size_t)(b*NB + qb*128 + w*16 + r)*2304 + h*HD + ks*32 + g*8];
  f32x4 oacc[6] = {};
  float m_run[4], l_run[4];
  #pragma unroll
  for (int j=0;j<4;++j){ m_run[j] = -1e30f; l_run[j] = 0.f; }
  // pb row base: row = qb*128 + w*16 + g*4 + j, col = kbase + n*16 + r
  const short* pbbase = pb + (size_t)(qb*128 + w*16 + g*4)*NB + r;
  // K staging source geometry
  int kc1row = t/6,        kc1off = (t%6)*8;
  int kc2row = (512+t)/6,  kc2off = ((512+t)%6)*8;
  // V staging source geometry (chunk-XOR pre-swizzled on global side)
  int vc1row = t>>3,        vc1off = ((t&7) ^ (vc1row&7))*8;
  int vc2row = (512+t)>>3,  vc2off = (((512+t)&7) ^ (vc2row&7))*8;
  const short* kbase_ptr = qkv + (size_t)(b*NB)*2304 + 768 + h*HD;
  const short* vbase_ptr = v_t + (size_t)((b*H + h)*HD)*NB;
  for (int kt=0; kt<32; ++kt){
    int kbase = kt*64;
    // pb prefetch (independent of LDS staging; latency hides under staging+MFMA)
    float pbv[4][4];
    #pragma unroll
    for (int j=0;j<4;++j)
      #pragma unroll
      for (int n=0;n<4;++n)
        pbv[j][n] = b2f(pbbase[(size_t)j*NB + kbase + n*16]);
    // stage K (768 chunks of 16B: 512 + 256)
    gload16(kbase_ptr + (size_t)(kbase + kc1row)*2304 + kc1off, (char*)Ks + w*1024);
    if (t < 256)
      gload16(kbase_ptr + (size_t)(kbase + kc2row)*2304 + kc2off, (char*)Ks + 8192 + w*1024);
    // stage V
    gload16(vbase_ptr + (size_t)vc1row*NB + kbase + vc1off, (char*)Vs + w*1024);
    if (t < 256)
      gload16(vbase_ptr + (size_t)vc2row*NB + kbase + vc2off, (char*)Vs + 8192 + w*1024);
    __syncthreads();
    // QK^T
    f32x4 sacc[4] = {};
    __builtin_amdgcn_s_setprio(1);
    #pragma unroll
    for (int ks=0;ks<3;++ks){
      short8 kb[4];
      #pragma unroll
      for (int n=0;n<4;++n) kb[n] = *(const short8*)&Ks[n*16 + r][ks*32 + g*8];
      #pragma unroll
      for (int n=0;n<4;++n)
        sacc[n] = __builtin_amdgcn_mfma_f32_16x16x32_bf16(qa[ks], kb[n], sacc[n], 0,0,0);
    }
    __builtin_amdgcn_s_setprio(0);
    // softmax (log2 domain), defer-max
    float vals[4][4], pmax[4];
    #pragma unroll
    for (int j=0;j<4;++j){
      #pragma unroll
      for (int n=0;n<4;++n)
        vals[j][n] = fmaf(sacc[n][j], SCALE2, pbv[j][n]);
      float pm = fmaxf(fmaxf(vals[j][0],vals[j][1]), fmaxf(vals[j][2],vals[j][3]));
      pm = fmaxf(pm, __shfl_xor(pm,1));
      pm = fmaxf(pm, __shfl_xor(pm,2));
      pm = fmaxf(pm, __shfl_xor(pm,4));
      pm = fmaxf(pm, __shfl_xor(pm,8));
      pmax[j] = pm;
    }
    float need = pmax[0]-m_run[0];
    need = fmaxf(need, pmax[1]-m_run[1]);
    need = fmaxf(need, pmax[2]-m_run[2]);
    need = fmaxf(need, pmax[3]-m_run[3]);
    if (__any(need > 8.f)){
      #pragma unroll
      for (int j=0;j<4;++j){
        float mn = fmaxf(m_run[j], pmax[j]);
        float f = fexp2(m_run[j] - mn);
        l_run[j] *= f; m_run[j] = mn;
        #pragma unroll
        for (int n=0;n<6;++n) oacc[n][j] *= f;
      }
    }
    #pragma unroll
    for (int j=0;j<4;++j){
      float rs = 0.f;
      #pragma unroll
      for (int n=0;n<4;++n){
        float pe = fexp2(vals[j][n] - m_run[j]);
        rs += pe;
        Ps[w][g*4 + j][n*16 + r] = f2b(pe);
      }
      rs += __shfl_xor(rs,1); rs += __shfl_xor(rs,2);
      rs += __shfl_xor(rs,4); rs += __shfl_xor(rs,8);
      l_run[j] += rs;
    }
    // PV (Ps per-wave; no cross-wave barrier needed)
    __builtin_amdgcn_s_setprio(1);
    #pragma unroll
    for (int ks2=0;ks2<2;++ks2){
      short8 pa = *(const short8*)&Ps[w][r][ks2*32 + g*8];
      #pragma unroll
      for (int n=0;n<6;++n){
        short8 vb = *(const short8*)&Vs[n*16 + r][((ks2*4 + g) ^ (r&7))*8];
        oacc[n] = __builtin_amdgcn_mfma_f32_16x16x32_bf16(pa, vb, oacc[n], 0,0,0);
      }
    }
    __builtin_amdgcn_s_setprio(0);
    __syncthreads();
  }
  #pragma unroll
  for (int j=0;j<4;++j){
    float inv = 1.f / l_run[j];
    #pragma unroll
    for (int n=0;n<6;++n){
      int rowg = b*NB + qb*128 + w*16 + g*4 + j;
      int col = h*HD + n*16 + r;
      aout[(size_t)rowg*D + col] = f2b(oacc[n][j]*inv);
    }
  }
}

extern "C" void kernel_launch(void* const* d_in, const int* in_sizes, int n_in,
                              void* d_out, int out_size, void* d_ws, size_t ws_size,
                              hipStream_t stream){
  const float* x   = (const float*)d_in[0];
  const float* pb  = (const float*)d_in[1];
  const float* wq  = (const float*)d_in[2];
  const float* bq  = (const float*)d_in[3];
  const float* wk  = (const float*)d_in[4];
  const float* bk  = (const float*)d_in[5];
  const float* wv  = (const float*)d_in[6];
  const float* bv  = (const float*)d_in[7];
  const float* wo  = (const float*)d_in[8];
  const float* bo  = (const float*)d_in[9];
  const float* g1  = (const float*)d_in[10];
  const float* b1  = (const float*)d_in[11];
  const float* g2  = (const float*)d_in[12];
  const float* b2  = (const float*)d_in[13];
  const float* wf1 = (const float*)d_in[14];
  const float* bf1 = (const float*)d_in[15];
  const float* wf2 = (const float*)d_in[16];
  const float* bf2 = (const float*)d_in[17];
  float* out = (float*)d_out;

  char* p = (char*)d_ws;
  auto alloc = [&](size_t bytes){ char* q = p; p += (bytes + 255) & ~(size_t)255; return q; };
  short* wqkv_t = (short*)alloc((size_t)2304*768*2);
  short* wo_t   = (short*)alloc((size_t)768*768*2);
  short* w1_t   = (short*)alloc((size_t)3072*768*2);
  short* w2_t   = (short*)alloc((size_t)768*3072*2);
  float* bqkv   = (float*)alloc(2304*4);
  short* pb16   = (short*)alloc((size_t)2048*2048*2);
  short* n1     = (short*)alloc((size_t)8192*768*2);   // reused as attn_out
  float* x1     = (float*)alloc((size_t)8192*768*4);
  short* n2     = (short*)alloc((size_t)8192*768*2);
  short* qkv    = (short*)alloc((size_t)8192*2304*2);
  short* v_t    = (short*)alloc((size_t)32*96*2048*2);
  short* hbuf   = qkv;      // aliases qkv+v_t (both dead after attention)
  short* attn_o = n1;       // n1 dead after QKV GEMM

  wtrans<<<dim3(24,24),256,0,stream>>>(wq, wqkv_t,               768, 768);
  wtrans<<<dim3(24,24),256,0,stream>>>(wk, wqkv_t + 768*768,     768, 768);
  wtrans<<<dim3(24,24),256,0,stream>>>(wv, wqkv_t + 2*768*768,   768, 768);
  wtrans<<<dim3(24,24),256,0,stream>>>(wo, wo_t, 768, 768);
  wtrans<<<dim3(24,96),256,0,stream>>>(wf1, w1_t, 768, 3072);
  wtrans<<<dim3(96,24),256,0,stream>>>(wf2, w2_t, 3072, 768);
  bias_cat<<<3,256,0,stream>>>(bq,bk,bv,bqkv);
  cvt_pb<<<4096,256,0,stream>>>(pb, pb16);
  ln_k<<<8192,256,0,stream>>>(x, g1, b1, n1);
  gemm_bt<0><<<dim3(64,18),256,0,stream>>>(n1, wqkv_t, bqkv, nullptr, qkv, 2304, 768);
  vtrans<<<1024,256,0,stream>>>(qkv, v_t);
  attn_k<<<512,512,0,stream>>>(qkv, v_t, pb16, attn_o);
  gemm_bt<1><<<dim3(64,6),256,0,stream>>>(attn_o, wo_t, bo, x, x1, 768, 768);
  ln_k<<<8192,256,0,stream>>>(x1, g2, b2, n2);
  gemm_bt<2><<<dim3(64,24),256,0,stream>>>(n2, w1_t, bf1, nullptr, hbuf, 3072, 768);
  gemm_bt<3><<<dim3(64,6),256,0,stream>>>(hbuf, w2_t, bf2, x1, out, 768, 3072);
}

// Round 3
// 372.898 us; speedup vs baseline: 1.0878x; 1.0387x over previous
//
#include <hip/hip_runtime.h>
#include <hip/hip_bf16.h>

#define D 768
#define H 8
#define HD 96
#define MLP 3072
#define NB 2048
#define BATCH 4

typedef __attribute__((ext_vector_type(8))) short short8;
typedef __attribute__((ext_vector_type(4))) short short4v;
typedef __attribute__((ext_vector_type(4))) float f32x4;

typedef const __attribute__((address_space(1))) unsigned int gu32;
typedef __attribute__((address_space(3))) unsigned int lu32;

__device__ inline void gload16(const void* g, void* l){
  __builtin_amdgcn_global_load_lds((gu32*)g, (lu32*)l, 16, 0, 0);
}

__device__ inline short f2b(float f){
  __hip_bfloat16 h = __float2bfloat16(f);
  return *reinterpret_cast<short*>(&h);
}
__device__ inline float b2f(short s){
  return __uint_as_float(((unsigned)(unsigned short)s) << 16);
}
__device__ inline float fexp2(float x){ return __builtin_amdgcn_exp2f(x); }

// ---- weight transpose+convert: f32 in[K][Nc] -> bf16 out[Nc][K] (B^T layout)
__global__ __launch_bounds__(256) void wtrans(const float* __restrict__ in, short* __restrict__ out, int K, int Nc){
  __shared__ float tile[32][33];
  int bk = blockIdx.x, bn = blockIdx.y;
  int tx = threadIdx.x & 31, ty = threadIdx.x >> 5;
  #pragma unroll
  for (int i=0;i<4;++i)
    tile[ty + i*8][tx] = in[(size_t)(bk*32 + ty + i*8)*Nc + bn*32 + tx];
  __syncthreads();
  #pragma unroll
  for (int i=0;i<4;++i)
    out[(size_t)(bn*32 + ty + i*8)*K + bk*32 + tx] = f2b(tile[tx][ty + i*8]);
}

__global__ __launch_bounds__(256) void bias_cat(const float* __restrict__ bq, const float* __restrict__ bk,
                                                const float* __restrict__ bv, float* __restrict__ o){
  int i = blockIdx.x*256 + threadIdx.x;
  if (i < 768){ o[i]=bq[i]; o[768+i]=bk[i]; o[1536+i]=bv[i]; }
}

// position bias -> bf16, pre-multiplied by log2(e) (softmax runs in log2 domain)
__global__ __launch_bounds__(256) void cvt_pb(const float* __restrict__ in, short* __restrict__ out){
  int i = blockIdx.x*256 + threadIdx.x;
  const float L2E = 1.4426950408889634f;
  f32x4 v = *(const f32x4*)&in[(size_t)i*4];
  short4v o;
  o[0]=f2b(v[0]*L2E); o[1]=f2b(v[1]*L2E); o[2]=f2b(v[2]*L2E); o[3]=f2b(v[3]*L2E);
  *(short4v*)&out[(size_t)i*4] = o;
}

// ---- LayerNorm: f32 [rows][768] -> bf16
__global__ __launch_bounds__(256) void ln_k(const float* __restrict__ X, const float* __restrict__ gg,
                                            const float* __restrict__ bb, short* __restrict__ out){
  int row = blockIdx.x, t = threadIdx.x;
  const float* x = X + (size_t)row*D;
  float v0=x[t], v1=x[t+256], v2=x[t+512];
  float s=v0+v1+v2, ss=v0*v0+v1*v1+v2*v2;
  #pragma unroll
  for (int m=1;m<64;m<<=1){ s += __shfl_xor(s,m); ss += __shfl_xor(ss,m); }
  __shared__ float red[8];
  int w=t>>6, lane=t&63;
  if (!lane){ red[w]=s; red[4+w]=ss; }
  __syncthreads();
  s = red[0]+red[1]+red[2]+red[3];
  ss = red[4]+red[5]+red[6]+red[7];
  float mu = s*(1.f/768.f);
  float inv = rsqrtf(ss*(1.f/768.f) - mu*mu + 1e-5f);
  short* o = out + (size_t)row*D;
  o[t]     = f2b((v0-mu)*inv*gg[t]     + bb[t]);
  o[t+256] = f2b((v1-mu)*inv*gg[t+256] + bb[t+256]);
  o[t+512] = f2b((v2-mu)*inv*gg[t+512] + bb[t+512]);
}

// ---- GEMM 128x128 (m97 structure): C = A[M][K] @ Bt[Nc][K]^T + bias
// MODE 0: +bias -> bf16 | MODE 2: +bias, erf-GELU -> bf16
template<int MODE>
__global__ __launch_bounds__(256) void gemm_bt(
    const short* __restrict__ A, const short* __restrict__ Bt,
    const float* __restrict__ bias, const float* __restrict__ resid,
    void* __restrict__ Cout, int Nc, int K)
{
  __shared__ __align__(16) short As[128][32];
  __shared__ __align__(16) short Bs[128][32];
  int m0 = blockIdx.x*128, n0 = blockIdx.y*128;
  int t = threadIdx.x;
  int lane = t & 63, w = t >> 6;
  int wm = w >> 1, wn = w & 1;
  int r = lane & 15, g = lane >> 4;
  const short* aSrc = A  + (size_t)(m0 + (t>>2))*K + (t&3)*8;
  const short* bSrc = Bt + (size_t)(n0 + (t>>2))*K + (t&3)*8;
  char* aDst0 = (char*)As + w*1024;
  char* aDst1 = (char*)As + 4096 + w*1024;
  char* bDst0 = (char*)Bs + w*1024;
  char* bDst1 = (char*)Bs + 4096 + w*1024;
  size_t rowK64 = (size_t)64*K;
  f32x4 acc[4][4] = {};
  for (int kt=0; kt<K; kt+=32){
    gload16(aSrc + kt,          aDst0);
    gload16(aSrc + kt + rowK64, aDst1);
    gload16(bSrc + kt,          bDst0);
    gload16(bSrc + kt + rowK64, bDst1);
    __syncthreads();
    short8 af[4], bfr[4];
    #pragma unroll
    for (int i=0;i<4;++i){
      af[i]  = *(const short8*)&As[wm*64 + i*16 + r][g*8];
      bfr[i] = *(const short8*)&Bs[wn*64 + i*16 + r][g*8];
    }
    #pragma unroll
    for (int i=0;i<4;++i)
      #pragma unroll
      for (int j=0;j<4;++j)
        acc[i][j] = __builtin_amdgcn_mfma_f32_16x16x32_bf16(af[i], bfr[j], acc[i][j], 0,0,0);
    __syncthreads();
  }
  #pragma unroll
  for (int i=0;i<4;++i){
    #pragma unroll
    for (int j=0;j<4;++j){
      int col = n0 + wn*64 + j*16 + r;
      float bv = bias[col];
      #pragma unroll
      for (int q=0;q<4;++q){
        int row = m0 + wm*64 + i*16 + g*4 + q;
        size_t idx = (size_t)row*Nc + col;
        float val = acc[i][j][q] + bv;
        if constexpr (MODE==0){
          ((short*)Cout)[idx] = f2b(val);
        } else if constexpr (MODE==2){
          float ge = 0.5f*val*(1.f + erff(val*0.70710678118654752f));
          ((short*)Cout)[idx] = f2b(ge);
        }
      }
    }
  }
}

// ---- GEMM 64x128 tile (for thin-N / thin-M shapes; better block-count balance)
// MODE 1: +bias[col] +resid -> f32   | MODE 5: V-scatter, +bias[row] -> bf16 v_t
template<int MODE>
__global__ __launch_bounds__(256) void gemm64(
    const short* __restrict__ A, const short* __restrict__ Bt,
    const float* __restrict__ bias, const float* __restrict__ resid,
    void* __restrict__ Cout, int Nc, int K)
{
  __shared__ __align__(16) short As[64][32];
  __shared__ __align__(16) short Bs[128][32];
  int m0 = blockIdx.x*64, n0 = blockIdx.y*128;
  int t = threadIdx.x;
  int lane = t & 63, w = t >> 6;
  int r = lane & 15, g = lane >> 4;
  const short* aSrc = A  + (size_t)(m0 + (t>>2))*K + (t&3)*8;
  const short* bSrc = Bt + (size_t)(n0 + (t>>2))*K + (t&3)*8;
  char* aDst  = (char*)As + w*1024;
  char* bDst0 = (char*)Bs + w*1024;
  char* bDst1 = (char*)Bs + 4096 + w*1024;
  size_t rowK64 = (size_t)64*K;
  f32x4 acc[4][2] = {};
  for (int kt=0; kt<K; kt+=32){
    gload16(aSrc + kt,          aDst);
    gload16(bSrc + kt,          bDst0);
    gload16(bSrc + kt + rowK64, bDst1);
    __syncthreads();
    short8 af[4], bfr[2];
    #pragma unroll
    for (int i=0;i<4;++i) af[i] = *(const short8*)&As[i*16 + r][g*8];
    #pragma unroll
    for (int j=0;j<2;++j) bfr[j] = *(const short8*)&Bs[w*32 + j*16 + r][g*8];
    #pragma unroll
    for (int i=0;i<4;++i)
      #pragma unroll
      for (int j=0;j<2;++j)
        acc[i][j] = __builtin_amdgcn_mfma_f32_16x16x32_bf16(af[i], bfr[j], acc[i][j], 0,0,0);
    __syncthreads();
  }
  #pragma unroll
  for (int i=0;i<4;++i){
    #pragma unroll
    for (int j=0;j<2;++j){
      int col = n0 + w*32 + j*16 + r;
      #pragma unroll
      for (int q=0;q<4;++q){
        int row = m0 + i*16 + g*4 + q;
        if constexpr (MODE==1){
          size_t idx = (size_t)row*Nc + col;
          ((float*)Cout)[idx] = acc[i][j][q] + bias[col] + resid[idx];
        } else {  // MODE 5: row = d (h*96+hd), col = global token (b*2048+n)
          int hh = row / 96, hd = row - hh*96;
          int bb = col >> 11, nn = col & 2047;
          size_t idx = ((size_t)((bb*8 + hh)*96 + hd))*2048 + nn;
          ((short*)Cout)[idx] = f2b(acc[i][j][q] + bias[row]);
        }
      }
    }
  }
}

// ---- Flash attention: 512 thr = 8 waves x 16 q-rows; KVBLK=64; K dbuf, V pipelined
__global__ __launch_bounds__(512, 4) void attn_k(const short* __restrict__ qkv, const short* __restrict__ v_t,
                                                 const short* __restrict__ pb, short* __restrict__ aout){
  int bx = blockIdx.x;
  int qb = bx & 15, h = (bx>>4)&7, b = bx>>7;
  int t = threadIdx.x, lane = t&63, w = t>>6;
  int r = lane&15, g = lane>>4;
  __shared__ __align__(16) short Ks[2][64][96];   // double-buffered, linear
  __shared__ __align__(16) short Vs[96][64];      // single, chunk-XOR via source
  __shared__ __align__(16) short Ps[8][16][72];
  const float SCALE2 = 0.10206207261596575f * 1.4426950408889634f;  // 1/sqrt(96)*log2e
  short8 qa[3];
  #pragma unroll
  for (int ks=0;ks<3;++ks)
    qa[ks] = *(const short8*)&qkv[(size_t)(b*NB + qb*128 + w*16 + r)*1536 + h*HD + ks*32 + g*8];
  f32x4 oacc[6] = {};
  float m_run[4], l_run[4];
  #pragma unroll
  for (int j=0;j<4;++j){ m_run[j] = -1e30f; l_run[j] = 0.f; }
  const short* pbbase = pb + (size_t)(qb*128 + w*16 + g*4)*NB + r;
  // K tile: 64 rows x 12 chunks(16B); V tile: 96 rows x 8 chunks
  int kc1row = t/12,       kc1off = (t%12)*8;
  int kc2row = (512+t)/12, kc2off = ((512+t)%12)*8;
  int vrow1 = t>>3,        voff1 = ((t&7) ^ (vrow1&7))*8;
  int vrow2 = (512+t)>>3,  voff2 = (((512+t)&7) ^ (vrow2&7))*8;
  const short* kg = qkv + (size_t)(b*NB)*1536 + 768 + h*HD;
  const short* vg = v_t + (size_t)((b*H+h)*HD)*NB;
  bool wlow = (w < 4);
  // prologue: stage K tile 0 into buf 0
  gload16(kg + (size_t)kc1row*1536 + kc1off, (char*)Ks + w*1024);
  if (wlow) gload16(kg + (size_t)kc2row*1536 + kc2off, (char*)Ks + 8192 + w*1024);
  int cur = 0;
  for (int kt=0; kt<32; ++kt){
    int kbase = kt*64;
    __syncthreads();   // drains K(kt) stage (in flight for a full iteration)
    // pb loads (oldest vmem -> counted wait leaves K/V staging in flight)
    float pbv[4][4];
    #pragma unroll
    for (int j=0;j<4;++j)
      #pragma unroll
      for (int n=0;n<4;++n)
        pbv[j][n] = b2f(pbbase[(size_t)j*NB + kbase + n*16]);
    // K(kt+1) stage into other buffer
    if (kt < 31){
      const short* kgn = kg + (size_t)(kbase+64)*1536;
      char* kd = (char*)Ks + (cur^1)*12288;
      gload16(kgn + (size_t)kc1row*1536 + kc1off, kd + w*1024);
      if (wlow) gload16(kgn + (size_t)kc2row*1536 + kc2off, kd + 8192 + w*1024);
    }
    // V(kt) stage (consumed only after QK^T + softmax)
    gload16(vg + (size_t)vrow1*NB + kbase + voff1, (char*)Vs + w*1024);
    if (wlow) gload16(vg + (size_t)vrow2*NB + kbase + voff2, (char*)Vs + 8192 + w*1024);
    // QK^T on Ks[cur]
    f32x4 sacc[4] = {};
    __builtin_amdgcn_s_setprio(1);
    #pragma unroll
    for (int ks=0;ks<3;++ks){
      short8 kb[4];
      #pragma unroll
      for (int n=0;n<4;++n) kb[n] = *(const short8*)&Ks[cur][n*16 + r][ks*32 + g*8];
      #pragma unroll
      for (int n=0;n<4;++n)
        sacc[n] = __builtin_amdgcn_mfma_f32_16x16x32_bf16(qa[ks], kb[n], sacc[n], 0,0,0);
    }
    __builtin_amdgcn_s_setprio(0);
    // softmax (log2 domain), defer-max
    float vals[4][4], pmax[4];
    #pragma unroll
    for (int j=0;j<4;++j){
      #pragma unroll
      for (int n=0;n<4;++n)
        vals[j][n] = fmaf(sacc[n][j], SCALE2, pbv[j][n]);
      float pm = fmaxf(fmaxf(vals[j][0],vals[j][1]), fmaxf(vals[j][2],vals[j][3]));
      pm = fmaxf(pm, __shfl_xor(pm,1));
      pm = fmaxf(pm, __shfl_xor(pm,2));
      pm = fmaxf(pm, __shfl_xor(pm,4));
      pm = fmaxf(pm, __shfl_xor(pm,8));
      pmax[j] = pm;
    }
    float need = pmax[0]-m_run[0];
    need = fmaxf(need, pmax[1]-m_run[1]);
    need = fmaxf(need, pmax[2]-m_run[2]);
    need = fmaxf(need, pmax[3]-m_run[3]);
    if (__any(need > 8.f)){
      #pragma unroll
      for (int j=0;j<4;++j){
        float mn = fmaxf(m_run[j], pmax[j]);
        float f = fexp2(m_run[j] - mn);
        l_run[j] *= f; m_run[j] = mn;
        #pragma unroll
        for (int n=0;n<6;++n) oacc[n][j] *= f;
      }
    }
    #pragma unroll
    for (int j=0;j<4;++j){
      float rs = 0.f;
      #pragma unroll
      for (int n=0;n<4;++n){
        float pe = fexp2(vals[j][n] - m_run[j]);
        rs += pe;
        Ps[w][g*4 + j][n*16 + r] = f2b(pe);
      }
      rs += __shfl_xor(rs,1); rs += __shfl_xor(rs,2);
      rs += __shfl_xor(rs,4); rs += __shfl_xor(rs,8);
      l_run[j] += rs;
    }
    // ensure V staging landed (explicit; also drains K(kt+1) after ~full-iter flight)
    asm volatile("s_waitcnt vmcnt(0)" ::: "memory");
    // PV
    __builtin_amdgcn_s_setprio(1);
    #pragma unroll
    for (int ks2=0;ks2<2;++ks2){
      short8 pa = *(const short8*)&Ps[w][r][ks2*32 + g*8];
      #pragma unroll
      for (int n=0;n<6;++n){
        short8 vb = *(const short8*)&Vs[n*16 + r][((ks2*4 + g) ^ (r&7))*8];
        oacc[n] = __builtin_amdgcn_mfma_f32_16x16x32_bf16(pa, vb, oacc[n], 0,0,0);
      }
    }
    __builtin_amdgcn_s_setprio(0);
    cur ^= 1;
  }
  #pragma unroll
  for (int j=0;j<4;++j){
    float inv = 1.f / l_run[j];
    #pragma unroll
    for (int n=0;n<6;++n){
      int rowg = b*NB + qb*128 + w*16 + g*4 + j;
      int col = h*HD + n*16 + r;
      aout[(size_t)rowg*D + col] = f2b(oacc[n][j]*inv);
    }
  }
}

extern "C" void kernel_launch(void* const* d_in, const int* in_sizes, int n_in,
                              void* d_out, int out_size, void* d_ws, size_t ws_size,
                              hipStream_t stream){
  const float* x   = (const float*)d_in[0];
  const float* pb  = (const float*)d_in[1];
  const float* wq  = (const float*)d_in[2];
  const float* bq  = (const float*)d_in[3];
  const float* wk  = (const float*)d_in[4];
  const float* bk  = (const float*)d_in[5];
  const float* wv  = (const float*)d_in[6];
  const float* bv  = (const float*)d_in[7];
  const float* wo  = (const float*)d_in[8];
  const float* bo  = (const float*)d_in[9];
  const float* g1  = (const float*)d_in[10];
  const float* b1  = (const float*)d_in[11];
  const float* g2  = (const float*)d_in[12];
  const float* b2  = (const float*)d_in[13];
  const float* wf1 = (const float*)d_in[14];
  const float* bf1 = (const float*)d_in[15];
  const float* wf2 = (const float*)d_in[16];
  const float* bf2 = (const float*)d_in[17];
  float* out = (float*)d_out;

  char* p = (char*)d_ws;
  auto alloc = [&](size_t bytes){ char* q = p; p += (bytes + 255) & ~(size_t)255; return q; };
  short* wqkv_t = (short*)alloc((size_t)2304*768*2);   // wq_t | wk_t | wv_t
  short* wo_t   = (short*)alloc((size_t)768*768*2);
  short* w1_t   = (short*)alloc((size_t)3072*768*2);
  short* w2_t   = (short*)alloc((size_t)768*3072*2);
  float* bqkv   = (float*)alloc(2304*4);
  short* pb16   = (short*)alloc((size_t)2048*2048*2);
  float* x1     = (float*)alloc((size_t)8192*768*4);
  short* n2     = (short*)alloc((size_t)8192*768*2);
  short* n1     = (short*)alloc((size_t)8192*768*2);   // reused as attn_out
  short* qkv    = (short*)alloc((size_t)8192*1536*2);  // QK only
  short* v_t    = (short*)alloc((size_t)32*96*2048*2);
  short* hbuf   = n1;       // FF1 out aliases n1+qkv+v_t (49.2MB >= 48MB; all dead)
  short* attn_o = n1;
  short* wv_t   = wqkv_t + (size_t)2*768*768;

  wtrans<<<dim3(24,24),256,0,stream>>>(wq, wqkv_t,           768, 768);
  wtrans<<<dim3(24,24),256,0,stream>>>(wk, wqkv_t + 768*768, 768, 768);
  wtrans<<<dim3(24,24),256,0,stream>>>(wv, wv_t,             768, 768);
  wtrans<<<dim3(24,24),256,0,stream>>>(wo, wo_t, 768, 768);
  wtrans<<<dim3(24,96),256,0,stream>>>(wf1, w1_t, 768, 3072);
  wtrans<<<dim3(96,24),256,0,stream>>>(wf2, w2_t, 3072, 768);
  bias_cat<<<3,256,0,stream>>>(bq,bk,bv,bqkv);
  cvt_pb<<<4096,256,0,stream>>>(pb, pb16);
  ln_k<<<8192,256,0,stream>>>(x, g1, b1, n1);
  gemm_bt<0><<<dim3(64,12),256,0,stream>>>(n1, wqkv_t, bqkv, nullptr, qkv, 1536, 768);
  gemm64<5><<<dim3(12,64),256,0,stream>>>(wv_t, n1, bv, nullptr, v_t, 0, 768);
  attn_k<<<512,512,0,stream>>>(qkv, v_t, pb16, attn_o);
  gemm64<1><<<dim3(128,6),256,0,stream>>>(attn_o, wo_t, bo, x, x1, 768, 768);
  ln_k<<<8192,256,0,stream>>>(x1, g2, b2, n2);
  gemm_bt<2><<<dim3(64,24),256,0,stream>>>(n2, w1_t, bf1, nullptr, hbuf, 3072, 768);
  gemm64<1><<<dim3(128,6),256,0,stream>>>(hbuf, w2_t, bf2, x1, out, 768, 3072);
}

// Round 6
// 338.443 us; speedup vs baseline: 1.1985x; 1.1018x over previous
//
#include <hip/hip_runtime.h>
#include <hip/hip_bf16.h>

#define D 768
#define H 8
#define HD 96
#define MLP 3072
#define NB 2048
#define BATCH 4

typedef __attribute__((ext_vector_type(8))) short short8;
typedef __attribute__((ext_vector_type(4))) short short4v;
typedef __attribute__((ext_vector_type(4))) float f32x4;
typedef __attribute__((ext_vector_type(16))) float f32x16;
typedef __attribute__((ext_vector_type(4))) int int4v;

typedef const __attribute__((address_space(1))) unsigned int gu32;
typedef __attribute__((address_space(3))) unsigned int lu32;

__device__ inline void gload16(const void* g, void* l){
  __builtin_amdgcn_global_load_lds((gu32*)g, (lu32*)l, 16, 0, 0);
}

__device__ inline short f2b(float f){
  __hip_bfloat16 h = __float2bfloat16(f);
  return *reinterpret_cast<short*>(&h);
}
__device__ inline float b2f(short s){
  return __uint_as_float(((unsigned)(unsigned short)s) << 16);
}
__device__ inline float fexp2(float x){ return __builtin_amdgcn_exp2f(x); }

__device__ inline unsigned cvtpk(float lo, float hi){
  unsigned r;
  asm volatile("v_cvt_pk_bf16_f32 %0, %1, %2" : "=v"(r) : "v"(lo), "v"(hi));
  return r;
}

// ---- weight transpose+convert: f32 in[K][Nc] -> bf16 out[Nc][K] (B^T layout)
__global__ __launch_bounds__(256) void wtrans(const float* __restrict__ in, short* __restrict__ out, int K, int Nc){
  __shared__ float tile[32][33];
  int bk = blockIdx.x, bn = blockIdx.y;
  int tx = threadIdx.x & 31, ty = threadIdx.x >> 5;
  #pragma unroll
  for (int i=0;i<4;++i)
    tile[ty + i*8][tx] = in[(size_t)(bk*32 + ty + i*8)*Nc + bn*32 + tx];
  __syncthreads();
  #pragma unroll
  for (int i=0;i<4;++i)
    out[(size_t)(bn*32 + ty + i*8)*K + bk*32 + tx] = f2b(tile[tx][ty + i*8]);
}

__global__ __launch_bounds__(256) void bias_cat(const float* __restrict__ bq, const float* __restrict__ bk,
                                                const float* __restrict__ bv, float* __restrict__ o){
  int i = blockIdx.x*256 + threadIdx.x;
  if (i < 768){ o[i]=bq[i]; o[768+i]=bk[i]; o[1536+i]=bv[i]; }
}

// position bias -> bf16 fragment-order table, pre-multiplied by log2(e).
// pbT[qt][kb][lane][v]: v = tile*16 + reg; value = pb[qt*32 + (lane&31)]
//                        [kb*64 + tile*32 + 8*(reg>>2) + (reg&3) + 4*(lane>>5)]
__global__ __launch_bounds__(256) void pb_reorg(const float* __restrict__ pb, short* __restrict__ pbT){
  int qt = blockIdx.x, kb = blockIdx.y;
  int t = threadIdx.x;
  int l = t >> 2;
  int vbase = (t & 3) * 8;
  int q = qt*32 + (l & 31);
  int hi = l >> 5;
  const float L2E = 1.4426950408889634f;
  short8 o;
  #pragma unroll
  for (int j=0;j<8;++j){
    int v = vbase + j;
    int r = v & 15, tile = v >> 4;
    int k = kb*64 + tile*32 + 8*(r>>2) + (r&3) + 4*hi;
    o[j] = f2b(pb[(size_t)q*NB + k] * L2E);
  }
  *(short8*)&pbT[(((size_t)(qt*32 + kb))*64 + l)*32 + vbase] = o;
}

// ---- LayerNorm: f32 [rows][768] -> bf16
__global__ __launch_bounds__(256) void ln_k(const float* __restrict__ X, const float* __restrict__ gg,
                                            const float* __restrict__ bb, short* __restrict__ out){
  int row = blockIdx.x, t = threadIdx.x;
  const float* x = X + (size_t)row*D;
  float v0=x[t], v1=x[t+256], v2=x[t+512];
  float s=v0+v1+v2, ss=v0*v0+v1*v1+v2*v2;
  #pragma unroll
  for (int m=1;m<64;m<<=1){ s += __shfl_xor(s,m); ss += __shfl_xor(ss,m); }
  __shared__ float red[8];
  int w=t>>6, lane=t&63;
  if (!lane){ red[w]=s; red[4+w]=ss; }
  __syncthreads();
  s = red[0]+red[1]+red[2]+red[3];
  ss = red[4]+red[5]+red[6]+red[7];
  float mu = s*(1.f/768.f);
  float inv = rsqrtf(ss*(1.f/768.f) - mu*mu + 1e-5f);
  short* o = out + (size_t)row*D;
  o[t]     = f2b((v0-mu)*inv*gg[t]     + bb[t]);
  o[t+256] = f2b((v1-mu)*inv*gg[t+256] + bb[t+256]);
  o[t+512] = f2b((v2-mu)*inv*gg[t+512] + bb[t+512]);
}

// ---- GEMM 128x128 (m97 structure): C = A[M][K] @ Bt[Nc][K]^T + bias
// MODE 0: +bias -> bf16 | MODE 2: +bias, erf-GELU -> bf16
template<int MODE>
__global__ __launch_bounds__(256) void gemm_bt(
    const short* __restrict__ A, const short* __restrict__ Bt,
    const float* __restrict__ bias, const float* __restrict__ resid,
    void* __restrict__ Cout, int Nc, int K)
{
  __shared__ __align__(16) short As[128][32];
  __shared__ __align__(16) short Bs[128][32];
  int m0 = blockIdx.x*128, n0 = blockIdx.y*128;
  int t = threadIdx.x;
  int lane = t & 63, w = t >> 6;
  int wm = w >> 1, wn = w & 1;
  int r = lane & 15, g = lane >> 4;
  const short* aSrc = A  + (size_t)(m0 + (t>>2))*K + (t&3)*8;
  const short* bSrc = Bt + (size_t)(n0 + (t>>2))*K + (t&3)*8;
  char* aDst0 = (char*)As + w*1024;
  char* aDst1 = (char*)As + 4096 + w*1024;
  char* bDst0 = (char*)Bs + w*1024;
  char* bDst1 = (char*)Bs + 4096 + w*1024;
  size_t rowK64 = (size_t)64*K;
  f32x4 acc[4][4] = {};
  for (int kt=0; kt<K; kt+=32){
    gload16(aSrc + kt,          aDst0);
    gload16(aSrc + kt + rowK64, aDst1);
    gload16(bSrc + kt,          bDst0);
    gload16(bSrc + kt + rowK64, bDst1);
    __syncthreads();
    short8 af[4], bfr[4];
    #pragma unroll
    for (int i=0;i<4;++i){
      af[i]  = *(const short8*)&As[wm*64 + i*16 + r][g*8];
      bfr[i] = *(const short8*)&Bs[wn*64 + i*16 + r][g*8];
    }
    #pragma unroll
    for (int i=0;i<4;++i)
      #pragma unroll
      for (int j=0;j<4;++j)
        acc[i][j] = __builtin_amdgcn_mfma_f32_16x16x32_bf16(af[i], bfr[j], acc[i][j], 0,0,0);
    __syncthreads();
  }
  #pragma unroll
  for (int i=0;i<4;++i){
    #pragma unroll
    for (int j=0;j<4;++j){
      int col = n0 + wn*64 + j*16 + r;
      float bv = bias[col];
      #pragma unroll
      for (int q=0;q<4;++q){
        int row = m0 + wm*64 + i*16 + g*4 + q;
        size_t idx = (size_t)row*Nc + col;
        float val = acc[i][j][q] + bv;
        if constexpr (MODE==0){
          ((short*)Cout)[idx] = f2b(val);
        } else if constexpr (MODE==2){
          float ge = 0.5f*val*(1.f + erff(val*0.70710678118654752f));
          ((short*)Cout)[idx] = f2b(ge);
        }
      }
    }
  }
}

// ---- GEMM 64x128 tile (thin shapes; block-count balance)
// MODE 1: +bias[col] +resid -> f32   | MODE 5: V-scatter, +bias[row] -> bf16 v_t
template<int MODE>
__global__ __launch_bounds__(256) void gemm64(
    const short* __restrict__ A, const short* __restrict__ Bt,
    const float* __restrict__ bias, const float* __restrict__ resid,
    void* __restrict__ Cout, int Nc, int K)
{
  __shared__ __align__(16) short As[64][32];
  __shared__ __align__(16) short Bs[128][32];
  int m0 = blockIdx.x*64, n0 = blockIdx.y*128;
  int t = threadIdx.x;
  int lane = t & 63, w = t >> 6;
  int r = lane & 15, g = lane >> 4;
  const short* aSrc = A  + (size_t)(m0 + (t>>2))*K + (t&3)*8;
  const short* bSrc = Bt + (size_t)(n0 + (t>>2))*K + (t&3)*8;
  char* aDst  = (char*)As + w*1024;
  char* bDst0 = (char*)Bs + w*1024;
  char* bDst1 = (char*)Bs + 4096 + w*1024;
  size_t rowK64 = (size_t)64*K;
  f32x4 acc[4][2] = {};
  for (int kt=0; kt<K; kt+=32){
    gload16(aSrc + kt,          aDst);
    gload16(bSrc + kt,          bDst0);
    gload16(bSrc + kt + rowK64, bDst1);
    __syncthreads();
    short8 af[4], bfr[2];
    #pragma unroll
    for (int i=0;i<4;++i) af[i] = *(const short8*)&As[i*16 + r][g*8];
    #pragma unroll
    for (int j=0;j<2;++j) bfr[j] = *(const short8*)&Bs[w*32 + j*16 + r][g*8];
    #pragma unroll
    for (int i=0;i<4;++i)
      #pragma unroll
      for (int j=0;j<2;++j)
        acc[i][j] = __builtin_amdgcn_mfma_f32_16x16x32_bf16(af[i], bfr[j], acc[i][j], 0,0,0);
    __syncthreads();
  }
  #pragma unroll
  for (int i=0;i<4;++i){
    #pragma unroll
    for (int j=0;j<2;++j){
      int col = n0 + w*32 + j*16 + r;
      #pragma unroll
      for (int q=0;q<4;++q){
        int row = m0 + i*16 + g*4 + q;
        if constexpr (MODE==1){
          size_t idx = (size_t)row*Nc + col;
          ((float*)Cout)[idx] = acc[i][j][q] + bias[col] + resid[idx];
        } else {  // MODE 5: row = d (h*96+hd), col = global token (b*2048+n)
          int hh = row / 96, hd = row - hh*96;
          int bb = col >> 11, nn = col & 2047;
          size_t idx = ((size_t)((bb*8 + hh)*96 + hd))*2048 + nn;
          ((short*)Cout)[idx] = f2b(acc[i][j][q] + bias[row]);
        }
      }
    }
  }
}

// ---- Flash attention v6: 8 waves x 32 q-rows = 256 q/block; 32x32x16 MFMA;
//      swapped QK^T (S[k][q]); in-register softmax + P-pack via shfl_xor(32)
//      (permlane32_swap removed — semantics not HW-verified here);
//      K reg-staged to padded XOR-swizzled LDS dbuf; V gload-lds + source-XOR.
__global__ __launch_bounds__(512, 1) void attn_k(const short* __restrict__ qkv, const short* __restrict__ v_t,
                                                 const short* __restrict__ pbT, short* __restrict__ aout){
  int bx = blockIdx.x;
  int h = bx & 7, b = (bx>>3)&3, qb = bx>>5;
  int t = threadIdx.x, l = t & 63, w = t >> 6;
  int l31 = l & 31, hi = l >> 5, l7 = l & 7;
  __shared__ __align__(16) short Ks[2][64][128];  // padded rows, XOR-swizzled chunks
  __shared__ __align__(16) short Vs[96][64];      // [d][k], source-XOR swizzled
  const float SCALE2 = 0.10206207261596575f * 1.4426950408889634f;  // 1/sqrt(96)*log2e

  // Q fragments: B-operand of mfma(K,Q): lane holds Q[q=l31][d = ds*16 + hi*8 + j]
  int qRow = qb*256 + w*32 + l31;
  const short* qg = qkv + (size_t)(b*NB + qRow)*1536 + h*HD;
  short8 qa[6];
  #pragma unroll
  for (int ds=0; ds<6; ++ds)
    qa[ds] = *(const short8*)&qg[ds*16 + hi*8];

  f32x16 oacc[3] = {};
  float m_run = -3.0e38f, l_run = 0.f;

  // K staging geometry (768 chunks of 16B over 512 threads), reg-staged ds_write
  int r0 = t/12,        c0 = t%12;
  int s1 = 512 + t;
  int r1 = s1/12,       c1 = s1%12;
  int ldsK0 = r0*128 + (c0 ^ (r0&7))*8;
  int ldsK1 = r1*128 + (c1 ^ (r1&7))*8;
  const short* kgB = qkv + (size_t)(b*NB)*1536 + 768 + h*HD;
  bool wlow = (t < 256);
  // V staging geometry: dest wave-uniform (HW adds lane*16), source XOR-swizzled
  int vr0 = t>>3,  vc0 = t&7;
  int vr1 = (512+t)>>3, vc1 = (512+t)&7;
  const short* vgB = v_t + (size_t)((b*H+h)*HD)*NB;
  const short* vsrc0 = vgB + (size_t)vr0*NB + (vc0 ^ (vr0&7))*8;
  const short* vsrc1 = vgB + (size_t)vr1*NB + (vc1 ^ (vr1&7))*8;
  char* vdst0 = (char*)Vs + w*1024;           // wave-uniform
  char* vdst1 = (char*)Vs + 8192 + w*1024;    // wave-uniform
  // pbT per-lane base: qt = qb*8 + w
  const short* pbB = pbT + (((size_t)((qb*8 + w)*32))*64 + l)*32;

  // prologue: stage K(0) into Ks[0]
  {
    short8 ka = *(const short8*)&kgB[(size_t)r0*1536 + c0*8];
    short* ks0 = &Ks[0][0][0];
    *(short8*)(ks0 + ldsK0) = ka;
    if (wlow){
      short8 kb = *(const short8*)&kgB[(size_t)r1*1536 + c1*8];
      *(short8*)(ks0 + ldsK1) = kb;
    }
  }
  __syncthreads();

  for (int kt=0; kt<32; ++kt){
    int cur = kt & 1;
    int kbase = kt*64;
    // --- issue pbT loads (oldest), V stage, K(kt+1) reg loads
    const short* pbk = pbB + kt*2048;
    short8 pbr0 = *(const short8*)&pbk[0];
    short8 pbr1 = *(const short8*)&pbk[8];
    short8 pbr2 = *(const short8*)&pbk[16];
    short8 pbr3 = *(const short8*)&pbk[24];
    gload16(vsrc0 + kbase, vdst0);
    if (wlow) gload16(vsrc1 + kbase, vdst1);
    int kb2 = (kt < 31) ? (kbase + 64) : kbase;
    short8 kra = *(const short8*)&kgB[(size_t)(kb2 + r0)*1536 + c0*8];
    short8 krb = {};
    if (wlow) krb = *(const short8*)&kgB[(size_t)(kb2 + r1)*1536 + c1*8];

    // --- QK^T: S[k][q], A = K-frag from swizzled LDS, B = qa
    f32x16 sacc[2] = {};
    __builtin_amdgcn_s_setprio(1);
    #pragma unroll
    for (int tt=0; tt<2; ++tt){
      #pragma unroll
      for (int ds=0; ds<6; ++ds){
        short8 kf = *(const short8*)&Ks[cur][tt*32 + l31][((ds*2 + hi) ^ l7)*8];
        sacc[tt] = __builtin_amdgcn_mfma_f32_32x32x16_bf16(kf, qa[ds], sacc[tt], 0,0,0);
      }
    }
    __builtin_amdgcn_s_setprio(0);

    // --- softmax (log2 domain); lane owns full row q = l31 (kv-half per hi)
    float vals[2][16];
    #pragma unroll
    for (int tt=0; tt<2; ++tt)
      #pragma unroll
      for (int r=0; r<16; ++r){
        int v = tt*16 + r;
        short pv = (v<8)?pbr0[v]:(v<16)?pbr1[v-8]:(v<24)?pbr2[v-16]:pbr3[v-24];
        vals[tt][r] = fmaf(sacc[tt][r], SCALE2, b2f(pv));
      }
    float pm = vals[0][0];
    #pragma unroll
    for (int tt=0; tt<2; ++tt)
      #pragma unroll
      for (int r=0; r<16; ++r) pm = fmaxf(pm, vals[tt][r]);
    pm = fmaxf(pm, __shfl_xor(pm, 32));
    // defer-max rescale
    if (__any(pm - m_run > 8.f)){
      float mn = fmaxf(m_run, pm);
      float f = fexp2(m_run - mn);
      l_run *= f; m_run = mn;
      int fi = __float_as_int(f);
      #pragma unroll
      for (int reg=0; reg<16; ++reg){
        int q = (reg&3) + 8*(reg>>2) + 4*hi;
        float fr = __int_as_float(__builtin_amdgcn_ds_bpermute(q<<2, fi));
        oacc[0][reg] *= fr; oacc[1][reg] *= fr; oacc[2][reg] *= fr;
      }
    }
    float p[2][16];
    float rs = 0.f;
    #pragma unroll
    for (int tt=0; tt<2; ++tt)
      #pragma unroll
      for (int r=0; r<16; ++r){
        p[tt][r] = fexp2(vals[tt][r] - m_run);
        rs += p[tt][r];
      }
    rs += __shfl_xor(rs, 32);
    l_run += rs;

    // --- pack P -> PV A-fragments via shfl_xor(32) (direction-unambiguous)
    // lane needs P[q=l31][kv = ks*16 + hi*8 + j]:
    //   hi=0: [own G0 | partner G0]  (kv 0..3 | 4..7 of the 16-slice)
    //   hi=1: [partner G1 | own G1]  (kv 8..11 | 12..15)
    short8 pa[4];
    #pragma unroll
    for (int ks=0; ks<4; ++ks){
      int tt = ks>>1;
      int rb = (ks&1)*8;
      unsigned G0a = cvtpk(p[tt][rb+0], p[tt][rb+1]);
      unsigned G0b = cvtpk(p[tt][rb+2], p[tt][rb+3]);
      unsigned G1a = cvtpk(p[tt][rb+4], p[tt][rb+5]);
      unsigned G1b = cvtpk(p[tt][rb+6], p[tt][rb+7]);
      unsigned sG0a = (unsigned)__shfl_xor((int)G0a, 32);
      unsigned sG0b = (unsigned)__shfl_xor((int)G0b, 32);
      unsigned sG1a = (unsigned)__shfl_xor((int)G1a, 32);
      unsigned sG1b = (unsigned)__shfl_xor((int)G1b, 32);
      int4v wv;
      wv[0] = hi ? (int)sG1a : (int)G0a;
      wv[1] = hi ? (int)sG1b : (int)G0b;
      wv[2] = hi ? (int)G1a  : (int)sG0a;
      wv[3] = hi ? (int)G1b  : (int)sG0b;
      pa[ks] = __builtin_bit_cast(short8, wv);
    }

    // --- all staging visible to all waves (barrier drains gload-lds queues)
    __syncthreads();

    // --- PV: O[q][d] += P·V
    __builtin_amdgcn_s_setprio(1);
    #pragma unroll
    for (int dt=0; dt<3; ++dt){
      #pragma unroll
      for (int ks=0; ks<4; ++ks){
        short8 vb = *(const short8*)&Vs[dt*32 + l31][((ks*2 + hi) ^ l7)*8];
        oacc[dt] = __builtin_amdgcn_mfma_f32_32x32x16_bf16(pa[ks], vb, oacc[dt], 0,0,0);
      }
    }
    __builtin_amdgcn_s_setprio(0);

    // --- write K(kt+1) into other buffer; barrier also protects Vs WAR
    if (kt < 31){
      short* ksn = &Ks[cur^1][0][0];
      *(short8*)(ksn + ldsK0) = kra;
      if (wlow) *(short8*)(ksn + ldsK1) = krb;
      __syncthreads();
    }
  }

  // --- epilogue: normalize rows (gather 1/l per output row) and store
  float inv_self = 1.f / l_run;
  int ii = __float_as_int(inv_self);
  #pragma unroll
  for (int reg=0; reg<16; ++reg){
    int q = (reg&3) + 8*(reg>>2) + 4*hi;
    float invq = __int_as_float(__builtin_amdgcn_ds_bpermute(q<<2, ii));
    int rowg = b*NB + qb*256 + w*32 + q;
    #pragma unroll
    for (int dt=0; dt<3; ++dt){
      int col = h*HD + dt*32 + l31;
      aout[(size_t)rowg*D + col] = f2b(oacc[dt][reg] * invq);
    }
  }
}

extern "C" void kernel_launch(void* const* d_in, const int* in_sizes, int n_in,
                              void* d_out, int out_size, void* d_ws, size_t ws_size,
                              hipStream_t stream){
  const float* x   = (const float*)d_in[0];
  const float* pb  = (const float*)d_in[1];
  const float* wq  = (const float*)d_in[2];
  const float* bq  = (const float*)d_in[3];
  const float* wk  = (const float*)d_in[4];
  const float* bk  = (const float*)d_in[5];
  const float* wv  = (const float*)d_in[6];
  const float* bv  = (const float*)d_in[7];
  const float* wo  = (const float*)d_in[8];
  const float* bo  = (const float*)d_in[9];
  const float* g1  = (const float*)d_in[10];
  const float* b1  = (const float*)d_in[11];
  const float* g2  = (const float*)d_in[12];
  const float* b2  = (const float*)d_in[13];
  const float* wf1 = (const float*)d_in[14];
  const float* bf1 = (const float*)d_in[15];
  const float* wf2 = (const float*)d_in[16];
  const float* bf2 = (const float*)d_in[17];
  float* out = (float*)d_out;

  char* p = (char*)d_ws;
  auto alloc = [&](size_t bytes){ char* q = p; p += (bytes + 255) & ~(size_t)255; return q; };
  short* wqkv_t = (short*)alloc((size_t)2304*768*2);   // wq_t | wk_t | wv_t
  short* wo_t   = (short*)alloc((size_t)768*768*2);
  short* w1_t   = (short*)alloc((size_t)3072*768*2);
  short* w2_t   = (short*)alloc((size_t)768*3072*2);
  float* bqkv   = (float*)alloc(2304*4);
  short* pbT    = (short*)alloc((size_t)2048*2048*2);
  float* x1     = (float*)alloc((size_t)8192*768*4);
  short* n2     = (short*)alloc((size_t)8192*768*2);
  short* n1     = (short*)alloc((size_t)8192*768*2);   // reused as attn_out
  short* qkv    = (short*)alloc((size_t)8192*1536*2);  // QK only
  short* v_t    = (short*)alloc((size_t)32*96*2048*2);
  short* hbuf   = n1;       // FF1 out aliases n1+qkv+v_t (all dead by then)
  short* attn_o = n1;
  short* wv_t   = wqkv_t + (size_t)2*768*768;

  wtrans<<<dim3(24,24),256,0,stream>>>(wq, wqkv_t,           768, 768);
  wtrans<<<dim3(24,24),256,0,stream>>>(wk, wqkv_t + 768*768, 768, 768);
  wtrans<<<dim3(24,24),256,0,stream>>>(wv, wv_t,             768, 768);
  wtrans<<<dim3(24,24),256,0,stream>>>(wo, wo_t, 768, 768);
  wtrans<<<dim3(24,96),256,0,stream>>>(wf1, w1_t, 768, 3072);
  wtrans<<<dim3(96,24),256,0,stream>>>(wf2, w2_t, 3072, 768);
  bias_cat<<<3,256,0,stream>>>(bq,bk,bv,bqkv);
  pb_reorg<<<dim3(64,32),256,0,stream>>>(pb, pbT);
  ln_k<<<8192,256,0,stream>>>(x, g1, b1, n1);
  gemm_bt<0><<<dim3(64,12),256,0,stream>>>(n1, wqkv_t, bqkv, nullptr, qkv, 1536, 768);
  gemm64<5><<<dim3(12,64),256,0,stream>>>(wv_t, n1, bv, nullptr, v_t, 0, 768);
  attn_k<<<256,512,0,stream>>>(qkv, v_t, pbT, attn_o);
  gemm64<1><<<dim3(128,6),256,0,stream>>>(attn_o, wo_t, bo, x, x1, 768, 768);
  ln_k<<<8192,256,0,stream>>>(x1, g2, b2, n2);
  gemm_bt<2><<<dim3(64,24),256,0,stream>>>(n2, w1_t, bf1, nullptr, hbuf, 3072, 768);
  gemm64<1><<<dim3(128,6),256,0,stream>>>(hbuf, w2_t, bf2, x1, out, 768, 3072);
}